// Round 7
// baseline (5191.484 us; speedup 1.0000x reference)
//
#include <hip/hip_runtime.h>

#define BATCH 64
#define LEN   2048
#define NIN   128
#define NH    256

// ---------------------------------------------------------------------------
// XLA tanh: llvm_ir::EmitFastTanh(with_fma=TRUE) — the coherent pair
// {fmuladd Horner, clamp ±7.99881172180175781}. This is what XLA-GPU (and a
// host-JIT with FMA) emits for f32 tanh.
//   |x| < 0.0004 -> passthrough x (unclamped);
//   else r = xc*P(xc^2) / Q(xc^2), P,Q Horner via fused fma, IEEE f32 divide.
// fmaf lowers to v_fma_f32 (always fused; hipcc cannot split/reassociate).
// '/' stays IEEE-correct under default flags (v_div_scale/v_div_fmas seq).
// ---------------------------------------------------------------------------
__device__ __forceinline__ float tanh_xla_fma_f32(float x) {
  const float kClamp = 7.99881172180175781f;
  float xc = fmaxf(x, -kClamp);             // maxnum
  xc = fminf(xc, kClamp);                   // minnum
  float x2 = xc * xc;
  float num = fmaf(x2, -2.76076847742355e-16f, 2.00018790482477e-13f);
  num = fmaf(x2, num, -8.60467152213735e-11f);
  num = fmaf(x2, num, 5.12229709037114e-08f);
  num = fmaf(x2, num, 1.48572235717979e-05f);
  num = fmaf(x2, num, 6.37261928875436e-04f);
  num = fmaf(x2, num, 4.89352455891786e-03f);
  num = xc * num;
  float den = fmaf(x2, 1.19825839466702e-06f, 1.18534705686654e-04f);
  den = fmaf(x2, den, 2.26843463243900e-03f);
  den = fmaf(x2, den, 4.89352518554385e-03f);
  float r = num / den;                      // IEEE f32 divide
  return (fabsf(x) < 0.0004f) ? x : r;
}

// ---------------------------------------------------------------------------
// Kernel A: xw[l][b][h] = sum_i x[b][l][i] * Wx[h][i]
// Dot model: per output element a single-accumulator, i-ascending chain of
// FUSED fma starting from 0 — the per-element semantics of cuBLAS/hipBLASLt
// SGEMM tile kernels (no split-k at k=128, mn=33M) and of FMA-built Eigen.
// ---------------------------------------------------------------------------
constexpr int LC = 128;   // l-positions per block

__global__ __launch_bounds__(256, 2)
void xw_kernel(const float* __restrict__ x, const float* __restrict__ Wx,
               float* __restrict__ out) {
  const int j  = threadIdx.x;            // output channel 0..255
  const int b  = blockIdx.x & (BATCH - 1);
  const int lt = blockIdx.x >> 6;        // which l-chunk

  float w[NIN];
#pragma unroll
  for (int i = 0; i < NIN; i += 4)
    *(float4*)&w[i] = *(const float4*)&Wx[j * NIN + i];

  const float* xr = x + ((size_t)b * LEN + (size_t)lt * LC) * NIN;
  float* op = out + ((size_t)lt * LC * BATCH + b) * NH + j;

  for (int ll = 0; ll < LC; ++ll) {
    const float* xrow = xr + (size_t)ll * NIN;   // wave-uniform address
    float acc = 0.0f;
#pragma unroll
    for (int i = 0; i < NIN; ++i)
      acc = fmaf(xrow[i], w[i], acc);            // strict i-ascending fma chain
    op[(size_t)ll * BATCH * NH] = acc;
  }
}

// ---------------------------------------------------------------------------
// Kernel B: recurrence. One batch element per block, 256 threads (4 waves ->
// 1 wave/SIMD; __launch_bounds__(256,1) -> 512-VGPR budget, w[256]+temps fit
// with no scratch spill). Thread j: W_h row j in VGPRs (fully unrolled,
// static indices). hw = k-ascending single-accumulator fmaf chain;
// pre = (xw + hw) + bias left-assoc (matching (xw_step + h@W_h.T) + b_h);
// tanh = EmitFastTanh(with_fma=true). Hidden state double-buffered in LDS
// (broadcast reads, conflict-free), 1 barrier/step; next xw prefetched.
// ---------------------------------------------------------------------------
__global__ __launch_bounds__(256, 1)
void rnn_kernel(const float* __restrict__ Wh, const float* __restrict__ bh,
                const float* __restrict__ h0, float* __restrict__ io) {
  const int b = blockIdx.x;
  const int j = threadIdx.x;

  __shared__ __align__(16) float hbuf[2][NH];

  float w[NH];
#pragma unroll
  for (int k = 0; k < NH; k += 4)
    *(float4*)&w[k] = *(const float4*)&Wh[j * NH + k];

  const float bias = bh[j];
  hbuf[0][j] = h0[b * NH + j];
  __syncthreads();

  float* p = io + (size_t)b * NH + j;
  const size_t stride = (size_t)BATCH * NH;

  float xw = p[0];                              // xw for step 0
  int cur = 0;

  for (int l = 0; l < LEN; ++l) {
    const int ln = (l + 1 < LEN) ? (l + 1) : l;
    const float xw_next = p[(size_t)ln * stride];   // prefetch next xw

    const float4* hb = (const float4*)&hbuf[cur][0];
    float acc = 0.0f;
#pragma unroll
    for (int k4 = 0; k4 < NH / 4; ++k4) {       // fully unrolled: static idx
      float4 h4 = hb[k4];                       // LDS broadcast read
      acc = fmaf(h4.x, w[4 * k4    ], acc);     // strict k-ascending fma chain
      acc = fmaf(h4.y, w[4 * k4 + 1], acc);
      acc = fmaf(h4.z, w[4 * k4 + 2], acc);
      acc = fmaf(h4.w, w[4 * k4 + 3], acc);
    }
    float pre;
    {
#pragma clang fp contract(off)
      pre = (xw + acc) + bias;                  // ((xw + hW) + b) order
    }
    const float hn = tanh_xla_fma_f32(pre);

    p[(size_t)l * stride] = hn;                 // output for this step
    hbuf[cur ^ 1][j] = hn;                      // publish state
    __syncthreads();
    cur ^= 1;
    xw = xw_next;
  }
}

extern "C" void kernel_launch(void* const* d_in, const int* in_sizes, int n_in,
                              void* d_out, int out_size, void* d_ws, size_t ws_size,
                              hipStream_t stream) {
  // Resolve inputs BY SIZE (all element counts distinct) — immune to
  // dict-order surprises. Falls back to positional order on mismatch.
  const float* x  = (const float*)d_in[0];  // 64*2048*128 = 16777216
  const float* h0 = (const float*)d_in[1];  // 64*256     = 16384
  const float* Wx = (const float*)d_in[2];  // 256*128    = 32768
  const float* Wh = (const float*)d_in[3];  // 256*256    = 65536
  const float* bh = (const float*)d_in[4];  // 256
  for (int i = 0; i < n_in; ++i) {
    switch (in_sizes[i]) {
      case 16777216: x  = (const float*)d_in[i]; break;
      case 16384:    h0 = (const float*)d_in[i]; break;
      case 32768:    Wx = (const float*)d_in[i]; break;
      case 65536:    Wh = (const float*)d_in[i]; break;
      case 256:      bh = (const float*)d_in[i]; break;
      default: break;
    }
  }
  float* out = (float*)d_out;               // [2048, 64, 256] f32

  xw_kernel<<<dim3((LEN / LC) * BATCH), dim3(256), 0, stream>>>(x, Wx, out);
  rnn_kernel<<<dim3(BATCH), dim3(256), 0, stream>>>(Wh, bh, h0, out);
}

// Round 8
// 5155.347 us; speedup vs baseline: 1.0070x; 1.0070x over previous
//
#include <hip/hip_runtime.h>

#define BATCH 64
#define LEN   2048
#define NIN   128
#define NH    256

// ---------------------------------------------------------------------------
// FROZEN ARITHMETIC (R7: absmax == 0.0). Do not touch:
//  - dots: single-accumulator, k-ascending fmaf chains from 0
//  - pre = (xw + acc) + bias, left-assoc, no contraction
//  - tanh = EmitFastTanh(with_fma=true): clamp ±7.99881172180175781,
//    fmaf Horner, IEEE f32 divide, |x|<0.0004 passthrough
// ---------------------------------------------------------------------------
__device__ __forceinline__ float tanh_xla_fma_f32(float x) {
  const float kClamp = 7.99881172180175781f;
  float xc = fmaxf(x, -kClamp);
  xc = fminf(xc, kClamp);
  float x2 = xc * xc;
  float num = fmaf(x2, -2.76076847742355e-16f, 2.00018790482477e-13f);
  num = fmaf(x2, num, -8.60467152213735e-11f);
  num = fmaf(x2, num, 5.12229709037114e-08f);
  num = fmaf(x2, num, 1.48572235717979e-05f);
  num = fmaf(x2, num, 6.37261928875436e-04f);
  num = fmaf(x2, num, 4.89352455891786e-03f);
  num = xc * num;
  float den = fmaf(x2, 1.19825839466702e-06f, 1.18534705686654e-04f);
  den = fmaf(x2, den, 2.26843463243900e-03f);
  den = fmaf(x2, den, 4.89352518554385e-03f);
  float r = num / den;
  return (fabsf(x) < 0.0004f) ? x : r;
}

// Macro enumeration: keeps per-thread weight rows as named float4 SSA values
// (NOT an array) so they live in VGPRs. R7's float w[256] hit LLVM's SROA
// size limit -> scratch -> L2 reload every step (VGPR_Count was 140).
#define REP32(M) M(0) M(1) M(2) M(3) M(4) M(5) M(6) M(7) \
  M(8) M(9) M(10) M(11) M(12) M(13) M(14) M(15) \
  M(16) M(17) M(18) M(19) M(20) M(21) M(22) M(23) \
  M(24) M(25) M(26) M(27) M(28) M(29) M(30) M(31)
#define REP64(M) REP32(M) M(32) M(33) M(34) M(35) M(36) M(37) M(38) M(39) \
  M(40) M(41) M(42) M(43) M(44) M(45) M(46) M(47) \
  M(48) M(49) M(50) M(51) M(52) M(53) M(54) M(55) \
  M(56) M(57) M(58) M(59) M(60) M(61) M(62) M(63)

// ---------------------------------------------------------------------------
// Kernel A: xw[l][b][h] = sum_i x[b][l][i] * Wx[h][i]
// 32 named float4 weights in VGPRs; x-row loads are block-uniform
// (scalarizable); strict i-ascending fmaf chain (frozen).
// ---------------------------------------------------------------------------
constexpr int LC = 128;   // l-positions per block

__global__ __launch_bounds__(256, 2)
void xw_kernel(const float* __restrict__ x, const float* __restrict__ Wx,
               float* __restrict__ out) {
  const int j  = threadIdx.x;
  const int b  = blockIdx.x & (BATCH - 1);
  const int lt = blockIdx.x >> 6;

  const float4* wrow = (const float4*)&Wx[(size_t)j * NIN];
#define XWDECL(n) const float4 xw##n = wrow[n];
  REP32(XWDECL)
#undef XWDECL

  const float* xr = x + ((size_t)b * LEN + (size_t)lt * LC) * NIN;
  float* op = out + ((size_t)lt * LC * BATCH + b) * NH + j;

  for (int ll = 0; ll < LC; ++ll) {
    const float* xrow = xr + (size_t)ll * NIN;   // block-uniform address
    float acc = 0.0f;
#define XWSTEP(n) { \
      acc = fmaf(xrow[4*(n)    ], xw##n.x, acc); \
      acc = fmaf(xrow[4*(n) + 1], xw##n.y, acc); \
      acc = fmaf(xrow[4*(n) + 2], xw##n.z, acc); \
      acc = fmaf(xrow[4*(n) + 3], xw##n.w, acc); }
    REP32(XWSTEP)
#undef XWSTEP
    op[(size_t)ll * BATCH * NH] = acc;
  }
}

// ---------------------------------------------------------------------------
// Kernel B: recurrence. One batch/block, 256 threads (4 waves, 1 wave/SIMD;
// launch_bounds(256,1) -> 512-VGPR budget). W_h row j = 64 named float4 in
// VGPRs (~290 VGPRs total, no spill). Hidden state double-buffered in LDS
// (broadcast reads). Custom barrier: lgkmcnt(0)-only wait + raw s_barrier —
// does NOT drain the global store (vs __syncthreads's vmcnt(0)), saving
// ~400 cyc/step. asm memory fences sandwich the barrier so no LDS op
// crosses it at compile time.
// ---------------------------------------------------------------------------
__global__ __launch_bounds__(256, 1)
void rnn_kernel(const float* __restrict__ Wh, const float* __restrict__ bh,
                const float* __restrict__ h0, float* __restrict__ io) {
  const int b = blockIdx.x;
  const int j = threadIdx.x;

  __shared__ __align__(16) float hbuf[2][NH];

  const float4* wrow = (const float4*)&Wh[(size_t)j * NH];
#define WDECL(n) const float4 wv##n = wrow[n];
  REP64(WDECL)
#undef WDECL

  const float bias = bh[j];
  hbuf[0][j] = h0[b * NH + j];
  __syncthreads();

  float* p = io + (size_t)b * NH + j;
  const size_t stride = (size_t)BATCH * NH;

  float xw = p[0];
  int cur = 0;

  for (int l = 0; l < LEN; ++l) {
    const int ln = (l + 1 < LEN) ? (l + 1) : l;
    const float xw_next = p[(size_t)ln * stride];   // prefetch next xw

    const float4* hb = (const float4*)&hbuf[cur][0];
    float acc = 0.0f;
#define WSTEP(n) { float4 h4 = hb[n]; \
      acc = fmaf(h4.x, wv##n.x, acc); \
      acc = fmaf(h4.y, wv##n.y, acc); \
      acc = fmaf(h4.z, wv##n.z, acc); \
      acc = fmaf(h4.w, wv##n.w, acc); }
    REP64(WSTEP)
#undef WSTEP

    float pre;
    {
#pragma clang fp contract(off)
      pre = (xw + acc) + bias;                  // ((xw + hW) + b) order
    }
    const float hn = tanh_xla_fma_f32(pre);

    p[(size_t)l * stride] = hn;                 // fire-and-forget store
    hbuf[cur ^ 1][j] = hn;                      // publish state

    // lgkmcnt-only barrier: LDS write visible, global store left in flight.
    asm volatile("s_waitcnt lgkmcnt(0)" ::: "memory");
    __builtin_amdgcn_s_barrier();
    asm volatile("" ::: "memory");

    cur ^= 1;
    xw = xw_next;
  }
}

extern "C" void kernel_launch(void* const* d_in, const int* in_sizes, int n_in,
                              void* d_out, int out_size, void* d_ws, size_t ws_size,
                              hipStream_t stream) {
  // Resolve inputs BY SIZE (all element counts distinct).
  const float* x  = (const float*)d_in[0];  // 16777216
  const float* h0 = (const float*)d_in[1];  // 16384
  const float* Wx = (const float*)d_in[2];  // 32768
  const float* Wh = (const float*)d_in[3];  // 65536
  const float* bh = (const float*)d_in[4];  // 256
  for (int i = 0; i < n_in; ++i) {
    switch (in_sizes[i]) {
      case 16777216: x  = (const float*)d_in[i]; break;
      case 16384:    h0 = (const float*)d_in[i]; break;
      case 32768:    Wx = (const float*)d_in[i]; break;
      case 65536:    Wh = (const float*)d_in[i]; break;
      case 256:      bh = (const float*)d_in[i]; break;
      default: break;
    }
  }
  float* out = (float*)d_out;               // [2048, 64, 256] f32

  xw_kernel<<<dim3((LEN / LC) * BATCH), dim3(256), 0, stream>>>(x, Wx, out);
  rnn_kernel<<<dim3(BATCH), dim3(256), 0, stream>>>(Wh, bh, h0, out);
}